// Round 1
// baseline (146.843 us; speedup 1.0000x reference)
//
#include <hip/hip_runtime.h>

#define NN 128
#define CC_ 16
#define HH 32
#define WW 32
#define DD 4096   // 16*16*16 pooled features per sample
#define ND (NN*DD)

// ---------------------------------------------------------------------------
// Kernel 1: fused 2x2 avg-pool of mu_a/mu_b and exp(logvar_a)/exp(logvar_b).
//   ma[n,d] = mean of 2x2 window of mu_a
//   va[n,d] = sum of exp(logvar_a) over window / 16   (avgpool * 1/k^2)
// One thread per pooled output element (n,c,ho,wo); handles all 4 tensors.
// Thread 0 also zeroes d_out (it is poisoned 0xAA before every launch).
// ---------------------------------------------------------------------------
__global__ __launch_bounds__(256) void pool_kernel(
    const float* __restrict__ mu_a, const float* __restrict__ lv_a,
    const float* __restrict__ mu_b, const float* __restrict__ lv_b,
    float* __restrict__ ws, float* __restrict__ out)
{
    int t = blockIdx.x * 256 + threadIdx.x;
    if (t == 0) out[0] = 0.0f;

    int wo = t & 15;
    int ho = (t >> 4) & 15;
    int c  = (t >> 8) & 15;
    int n  = t >> 12;

    int base = ((n * CC_ + c) * HH + 2 * ho) * WW + 2 * wo;  // even -> 8B aligned

    float2 a0 = *(const float2*)(mu_a + base);
    float2 a1 = *(const float2*)(mu_a + base + WW);
    float2 la0 = *(const float2*)(lv_a + base);
    float2 la1 = *(const float2*)(lv_a + base + WW);
    float2 b0 = *(const float2*)(mu_b + base);
    float2 b1 = *(const float2*)(mu_b + base + WW);
    float2 lb0 = *(const float2*)(lv_b + base);
    float2 lb1 = *(const float2*)(lv_b + base + WW);

    float ma_v = 0.25f * (a0.x + a0.y + a1.x + a1.y);
    float mb_v = 0.25f * (b0.x + b0.y + b1.x + b1.y);
    float va_v = 0.0625f * (__expf(la0.x) + __expf(la0.y) + __expf(la1.x) + __expf(la1.y));
    float vb_v = 0.0625f * (__expf(lb0.x) + __expf(lb0.y) + __expf(lb1.x) + __expf(lb1.y));

    ws[t]          = ma_v;
    ws[ND + t]     = va_v;
    ws[2 * ND + t] = mb_v;
    ws[3 * ND + t] = vb_v;
}

// ---------------------------------------------------------------------------
// Kernel 2: fused pair sums. term = exp(-0.5*(d^2/s + log s))
//                                 = exp2(C * (d*rsqrt(s))^2) * rsqrt(s),
//   C = -0.5*log2(e). Each thread owns (i0..i0+3, d), loops over all j,
// computing aa + bb - 2*ab locally (good cancellation before reduction).
// Grid: x = 16 d-chunks of 256, y = 32 i-tiles of 4. 512 blocks.
// ---------------------------------------------------------------------------
__global__ __launch_bounds__(256) void pair_kernel(
    const float* __restrict__ ws, float* __restrict__ out)
{
    const float* __restrict__ ma = ws;
    const float* __restrict__ va = ws + ND;
    const float* __restrict__ mb = ws + 2 * ND;
    const float* __restrict__ vb = ws + 3 * ND;

    const int d  = blockIdx.x * 256 + threadIdx.x;
    const int i0 = blockIdx.y * 4;

    float rma[4], rva[4], rmb[4], rvb[4];
#pragma unroll
    for (int k = 0; k < 4; ++k) {
        rma[k] = ma[(i0 + k) * DD + d];
        rva[k] = va[(i0 + k) * DD + d];
        rmb[k] = mb[(i0 + k) * DD + d];
        rvb[k] = vb[(i0 + k) * DD + d];
    }

    const float Cneg = -0.7213475204444817f;  // -0.5 * log2(e)
    float acc_aa = 0.0f, acc_bb = 0.0f, acc_ab = 0.0f;

    for (int j = 0; j < NN; ++j) {
        float jma = ma[j * DD + d];
        float jva = va[j * DD + d];
        float jmb = mb[j * DD + d];
        float jvb = vb[j * DD + d];
#pragma unroll
        for (int k = 0; k < 4; ++k) {
            {   // aa
                float dd = rma[k] - jma;
                float s  = rva[k] + jva;
                float r  = __builtin_amdgcn_rsqf(s);
                float q  = dd * r;
                float e  = __builtin_amdgcn_exp2f(Cneg * q * q);
                acc_aa += e * r;
            }
            {   // bb
                float dd = rmb[k] - jmb;
                float s  = rvb[k] + jvb;
                float r  = __builtin_amdgcn_rsqf(s);
                float q  = dd * r;
                float e  = __builtin_amdgcn_exp2f(Cneg * q * q);
                acc_bb += e * r;
            }
            {   // ab
                float dd = rma[k] - jmb;
                float s  = rva[k] + jvb;
                float r  = __builtin_amdgcn_rsqf(s);
                float q  = dd * r;
                float e  = __builtin_amdgcn_exp2f(Cneg * q * q);
                acc_ab += e * r;
            }
        }
    }

    float part = acc_aa + acc_bb - 2.0f * acc_ab;

    // wave (64-lane) shuffle reduction
#pragma unroll
    for (int off = 32; off > 0; off >>= 1)
        part += __shfl_down(part, off, 64);

    __shared__ float wsum[4];
    int lane = threadIdx.x & 63;
    int wv   = threadIdx.x >> 6;
    if (lane == 0) wsum[wv] = part;
    __syncthreads();
    if (threadIdx.x == 0) {
        float s = wsum[0] + wsum[1] + wsum[2] + wsum[3];
        atomicAdd(out, s);
    }
}

extern "C" void kernel_launch(void* const* d_in, const int* in_sizes, int n_in,
                              void* d_out, int out_size, void* d_ws, size_t ws_size,
                              hipStream_t stream) {
    const float* mu_a = (const float*)d_in[0];
    const float* lv_a = (const float*)d_in[1];
    const float* mu_b = (const float*)d_in[2];
    const float* lv_b = (const float*)d_in[3];
    float* out = (float*)d_out;
    float* ws  = (float*)d_ws;

    // 524288 pooled outputs -> 2048 blocks of 256
    pool_kernel<<<dim3(ND / 256), 256, 0, stream>>>(mu_a, lv_a, mu_b, lv_b, ws, out);
    // 16 d-chunks x 32 i-tiles
    pair_kernel<<<dim3(DD / 256, NN / 4), 256, 0, stream>>>(ws, out);
}

// Round 4
// 133.962 us; speedup vs baseline: 1.0962x; 1.0962x over previous
//
#include <hip/hip_runtime.h>

#define NN 128
#define CC_ 16
#define HH 32
#define WW 32
#define DD 4096   // 16*16*16 pooled features per sample
#define ND (NN*DD)

// c = sqrt(0.5*log2(e)); folding it into the means turns the per-term
// exponent into exp2(-(q*q)) with the negate absorbed by the v_exp input
// modifier (free), saving one mul per term.
#define MU_SCALE 0.8493218002880191f

// ---------------------------------------------------------------------------
// Kernel 1: fused 2x2 avg-pool. Means are pre-scaled by MU_SCALE; variances
// are avgpool(exp(lv)) / k^2 (unscaled). Thread 0 zeroes d_out (poisoned).
// ---------------------------------------------------------------------------
__global__ __launch_bounds__(256) void pool_kernel(
    const float* __restrict__ mu_a, const float* __restrict__ lv_a,
    const float* __restrict__ mu_b, const float* __restrict__ lv_b,
    float* __restrict__ ws, float* __restrict__ out)
{
    int t = blockIdx.x * 256 + threadIdx.x;
    if (t == 0) out[0] = 0.0f;

    int wo = t & 15;
    int ho = (t >> 4) & 15;
    int c  = (t >> 8) & 15;
    int n  = t >> 12;

    int base = ((n * CC_ + c) * HH + 2 * ho) * WW + 2 * wo;  // even -> 8B aligned

    float2 a0 = *(const float2*)(mu_a + base);
    float2 a1 = *(const float2*)(mu_a + base + WW);
    float2 la0 = *(const float2*)(lv_a + base);
    float2 la1 = *(const float2*)(lv_a + base + WW);
    float2 b0 = *(const float2*)(mu_b + base);
    float2 b1 = *(const float2*)(mu_b + base + WW);
    float2 lb0 = *(const float2*)(lv_b + base);
    float2 lb1 = *(const float2*)(lv_b + base + WW);

    const float ms = 0.25f * MU_SCALE;
    float ma_v = ms * (a0.x + a0.y + a1.x + a1.y);
    float mb_v = ms * (b0.x + b0.y + b1.x + b1.y);
    float va_v = 0.0625f * (__expf(la0.x) + __expf(la0.y) + __expf(la1.x) + __expf(la1.y));
    float vb_v = 0.0625f * (__expf(lb0.x) + __expf(lb0.y) + __expf(lb1.x) + __expf(lb1.y));

    ws[t]          = ma_v;
    ws[ND + t]     = va_v;
    ws[2 * ND + t] = mb_v;
    ws[3 * ND + t] = vb_v;
}

// ---------------------------------------------------------------------------
// Kernel 2: fused pair sums.
//   term = exp2(-(c*d*rsqrt(s))^2) * rsqrt(s), c folded into means already.
// Each thread owns (i0..i0+3, d) and a 32-wide j-chunk.
// 2-D grid: x = 16 d-chunks; y = 128 encodes (i-tile, j-chunk):
//   i0 = (y >> 2) * 4, j0 = (y & 3) * 32.  2048 blocks -> 8 blocks/CU,
// 32 waves/CU (full occupancy at VGPR=28).
// ---------------------------------------------------------------------------
#define JCHUNK 32

__global__ __launch_bounds__(256) void pair_kernel(
    const float* __restrict__ ws, float* __restrict__ out)
{
    const float* __restrict__ ma = ws;
    const float* __restrict__ va = ws + ND;
    const float* __restrict__ mb = ws + 2 * ND;
    const float* __restrict__ vb = ws + 3 * ND;

    const int d  = blockIdx.x * 256 + threadIdx.x;
    const int i0 = (blockIdx.y >> 2) * 4;
    const int j0 = (blockIdx.y & 3) * JCHUNK;

    float rma[4], rva[4], rmb[4], rvb[4];
#pragma unroll
    for (int k = 0; k < 4; ++k) {
        rma[k] = ma[(i0 + k) * DD + d];
        rva[k] = va[(i0 + k) * DD + d];
        rmb[k] = mb[(i0 + k) * DD + d];
        rvb[k] = vb[(i0 + k) * DD + d];
    }

    float acc_aa = 0.0f, acc_bb = 0.0f, acc_ab = 0.0f;

    for (int j = j0; j < j0 + JCHUNK; ++j) {
        float jma = ma[j * DD + d];
        float jva = va[j * DD + d];
        float jmb = mb[j * DD + d];
        float jvb = vb[j * DD + d];
#pragma unroll
        for (int k = 0; k < 4; ++k) {
            {   // aa
                float dd = rma[k] - jma;
                float s  = rva[k] + jva;
                float r  = __builtin_amdgcn_rsqf(s);
                float q  = dd * r;
                float e  = __builtin_amdgcn_exp2f(-(q * q));
                acc_aa = fmaf(e, r, acc_aa);
            }
            {   // bb
                float dd = rmb[k] - jmb;
                float s  = rvb[k] + jvb;
                float r  = __builtin_amdgcn_rsqf(s);
                float q  = dd * r;
                float e  = __builtin_amdgcn_exp2f(-(q * q));
                acc_bb = fmaf(e, r, acc_bb);
            }
            {   // ab
                float dd = rma[k] - jmb;
                float s  = rva[k] + jvb;
                float r  = __builtin_amdgcn_rsqf(s);
                float q  = dd * r;
                float e  = __builtin_amdgcn_exp2f(-(q * q));
                acc_ab = fmaf(e, r, acc_ab);
            }
        }
    }

    float part = acc_aa + acc_bb - 2.0f * acc_ab;

    // wave (64-lane) shuffle reduction
#pragma unroll
    for (int off = 32; off > 0; off >>= 1)
        part += __shfl_down(part, off, 64);

    __shared__ float wsum[4];
    int lane = threadIdx.x & 63;
    int wv   = threadIdx.x >> 6;
    if (lane == 0) wsum[wv] = part;
    __syncthreads();
    if (threadIdx.x == 0) {
        float s = wsum[0] + wsum[1] + wsum[2] + wsum[3];
        atomicAdd(out, s);
    }
}

extern "C" void kernel_launch(void* const* d_in, const int* in_sizes, int n_in,
                              void* d_out, int out_size, void* d_ws, size_t ws_size,
                              hipStream_t stream) {
    const float* mu_a = (const float*)d_in[0];
    const float* lv_a = (const float*)d_in[1];
    const float* mu_b = (const float*)d_in[2];
    const float* lv_b = (const float*)d_in[3];
    float* out = (float*)d_out;
    float* ws  = (float*)d_ws;

    pool_kernel<<<dim3(ND / 256), 256, 0, stream>>>(mu_a, lv_a, mu_b, lv_b, ws, out);
    pair_kernel<<<dim3(DD / 256, (NN / 4) * (NN / JCHUNK)), 256, 0, stream>>>(ws, out);
}

// Round 5
// 123.765 us; speedup vs baseline: 1.1865x; 1.0824x over previous
//
#include <hip/hip_runtime.h>

#define NN 128
#define CC_ 16
#define HH 32
#define WW 32
#define DD 4096   // 16*16*16 pooled features per sample
#define ND (NN*DD)

typedef float v2f __attribute__((ext_vector_type(2)));

// c = sqrt(0.5*log2(e)); folded into the means so the per-term exponent is
// exp2(-(q*q)) with the negate absorbed by the v_exp input modifier.
#define MU_SCALE 0.8493218002880191f

// ---------------------------------------------------------------------------
// Kernel 1: fused 2x2 avg-pool, INTERLEAVED output layout for packed math:
//   wm[n*DD+d] = {MU_SCALE*ma, MU_SCALE*mb}   (float2)
//   wv[n*DD+d] = {va, vb}                     (float2), v = avgpool(exp(lv))/4
// Thread 0 zeroes d_out (poisoned 0xAA before every launch).
// ---------------------------------------------------------------------------
__global__ __launch_bounds__(256) void pool_kernel(
    const float* __restrict__ mu_a, const float* __restrict__ lv_a,
    const float* __restrict__ mu_b, const float* __restrict__ lv_b,
    float2* __restrict__ wm, float2* __restrict__ wv, float* __restrict__ out)
{
    int t = blockIdx.x * 256 + threadIdx.x;
    if (t == 0) out[0] = 0.0f;

    int wo = t & 15;
    int ho = (t >> 4) & 15;
    int c  = (t >> 8) & 15;
    int n  = t >> 12;

    int base = ((n * CC_ + c) * HH + 2 * ho) * WW + 2 * wo;  // even -> 8B aligned

    float2 a0 = *(const float2*)(mu_a + base);
    float2 a1 = *(const float2*)(mu_a + base + WW);
    float2 la0 = *(const float2*)(lv_a + base);
    float2 la1 = *(const float2*)(lv_a + base + WW);
    float2 b0 = *(const float2*)(mu_b + base);
    float2 b1 = *(const float2*)(mu_b + base + WW);
    float2 lb0 = *(const float2*)(lv_b + base);
    float2 lb1 = *(const float2*)(lv_b + base + WW);

    const float ms = 0.25f * MU_SCALE;
    float ma_v = ms * (a0.x + a0.y + a1.x + a1.y);
    float mb_v = ms * (b0.x + b0.y + b1.x + b1.y);
    float va_v = 0.0625f * (__expf(la0.x) + __expf(la0.y) + __expf(la1.x) + __expf(la1.y));
    float vb_v = 0.0625f * (__expf(lb0.x) + __expf(lb0.y) + __expf(lb1.x) + __expf(lb1.y));

    wm[t] = make_float2(ma_v, mb_v);
    wv[t] = make_float2(va_v, vb_v);
}

// ---------------------------------------------------------------------------
// Kernel 2: fused pair sums with packed-f32 (VOP3P) math.
//   term = exp2(-(q*q)) * r,  q = dd*r, r = rsqrt(s)  (scale pre-folded)
// Each v2f group computes TWO terms (k and k+1 of the 4-row i-tile) with
// v_pk_add/mul/fma_f32; rsq/exp stay scalar (no packed trans).
// Grid: x = 16 d-chunks; y = 128 = (i-tile, j-chunk): 2048 blocks.
// ---------------------------------------------------------------------------
#define JCHUNK 32

__device__ __forceinline__ void pair_group(
    v2f& acc, v2f mi, v2f mj, v2f vi, v2f vj)
{
    v2f dd = mi - mj;          // v_pk_add (neg)
    v2f s  = vi + vj;          // v_pk_add
    v2f r;
    r.x = __builtin_amdgcn_rsqf(s.x);
    r.y = __builtin_amdgcn_rsqf(s.y);
    v2f q  = dd * r;           // v_pk_mul
    v2f qq = q * q;            // v_pk_mul
    v2f e;
    e.x = __builtin_amdgcn_exp2f(-qq.x);
    e.y = __builtin_amdgcn_exp2f(-qq.y);
    acc += e * r;              // v_pk_fma
}

__global__ __launch_bounds__(256) void pair_kernel(
    const float2* __restrict__ wm, const float2* __restrict__ wv,
    float* __restrict__ out)
{
    const int d  = blockIdx.x * 256 + threadIdx.x;
    const int i0 = (blockIdx.y >> 2) * 4;
    const int j0 = (blockIdx.y & 3) * JCHUNK;

    // Load 4 i-rows, repack by tensor: pma[p] = {ma[i0+2p], ma[i0+2p+1]} etc.
    v2f pma[2], pmb[2], pva[2], pvb[2];
#pragma unroll
    for (int p = 0; p < 2; ++p) {
        float2 m0 = wm[(i0 + 2 * p) * DD + d];
        float2 m1 = wm[(i0 + 2 * p + 1) * DD + d];
        float2 v0 = wv[(i0 + 2 * p) * DD + d];
        float2 v1 = wv[(i0 + 2 * p + 1) * DD + d];
        pma[p] = (v2f){m0.x, m1.x};
        pmb[p] = (v2f){m0.y, m1.y};
        pva[p] = (v2f){v0.x, v1.x};
        pvb[p] = (v2f){v0.y, v1.y};
    }

    v2f acc_aa = (v2f){0.0f, 0.0f};
    v2f acc_bb = (v2f){0.0f, 0.0f};
    v2f acc_ab = (v2f){0.0f, 0.0f};

#pragma unroll 2
    for (int j = j0; j < j0 + JCHUNK; ++j) {
        float2 jm = wm[j * DD + d];   // {jma, jmb} one 8B load
        float2 jv = wv[j * DD + d];   // {jva, jvb}
        v2f jma2 = (v2f){jm.x, jm.x};
        v2f jmb2 = (v2f){jm.y, jm.y};
        v2f jva2 = (v2f){jv.x, jv.x};
        v2f jvb2 = (v2f){jv.y, jv.y};
#pragma unroll
        for (int p = 0; p < 2; ++p) {
            pair_group(acc_aa, pma[p], jma2, pva[p], jva2);
            pair_group(acc_bb, pmb[p], jmb2, pvb[p], jvb2);
            pair_group(acc_ab, pma[p], jmb2, pva[p], jvb2);
        }
    }

    float part = (acc_aa.x + acc_aa.y) + (acc_bb.x + acc_bb.y)
               - 2.0f * (acc_ab.x + acc_ab.y);

    // wave (64-lane) shuffle reduction
#pragma unroll
    for (int off = 32; off > 0; off >>= 1)
        part += __shfl_down(part, off, 64);

    __shared__ float wsum[4];
    int lane = threadIdx.x & 63;
    int wv_  = threadIdx.x >> 6;
    if (lane == 0) wsum[wv_] = part;
    __syncthreads();
    if (threadIdx.x == 0) {
        float s = wsum[0] + wsum[1] + wsum[2] + wsum[3];
        atomicAdd(out, s);
    }
}

extern "C" void kernel_launch(void* const* d_in, const int* in_sizes, int n_in,
                              void* d_out, int out_size, void* d_ws, size_t ws_size,
                              hipStream_t stream) {
    const float* mu_a = (const float*)d_in[0];
    const float* lv_a = (const float*)d_in[1];
    const float* mu_b = (const float*)d_in[2];
    const float* lv_b = (const float*)d_in[3];
    float* out = (float*)d_out;
    float2* wm = (float2*)d_ws;            // ND float2 = 4 MB
    float2* wv = ((float2*)d_ws) + ND;     // ND float2 = 4 MB

    pool_kernel<<<dim3(ND / 256), 256, 0, stream>>>(mu_a, lv_a, mu_b, lv_b, wm, wv, out);
    pair_kernel<<<dim3(DD / 256, (NN / 4) * (NN / JCHUNK)), 256, 0, stream>>>(wm, wv, out);
}